// Round 15
// baseline (361.633 us; speedup 1.0000x reference)
//
#include <hip/hip_runtime.h>
#include <hip/hip_bf16.h>

#define NN 50000
#define NE 800000
#define BN_EPS 1e-5f
#define CHUNK 4096
#define NCH 196    // ceil(NE / CHUNK) = 196 (196*4096 = 802816)
#define NBK 196    // ceil(NN / 256) dst-buckets

typedef __attribute__((ext_vector_type(4))) float f32x4;
typedef __attribute__((ext_vector_type(8))) short s16x8;   // 8 bf16 = MFMA A/B frag
typedef __attribute__((ext_vector_type(4))) short s16x4;

__device__ __forceinline__ float bf2f(__hip_bfloat16 v) { return __bfloat162float(v); }
__device__ __forceinline__ float bs2f(short v) {
    unsigned u = ((unsigned)(unsigned short)v) << 16;
    return __builtin_bit_cast(float, u);
}
__device__ __forceinline__ short f2bs(float v) {
    __hip_bfloat16 b = __float2bfloat16(v);
    return __builtin_bit_cast(short, b);
}

// ---- prep: [0,196) bhist chunks -> part; [196,3321) cvt x->Xb; [3321,3326) W^T->bf16
__global__ void prep_k(const int* __restrict__ dst, int* __restrict__ part,
                       const float* __restrict__ x, __hip_bfloat16* __restrict__ Xb,
                       const float* __restrict__ w0a, const float* __restrict__ w0b,
                       const float* __restrict__ w1a, const float* __restrict__ w1b,
                       const float* __restrict__ lw,
                       short* __restrict__ Wt0a, short* __restrict__ Wt0b,
                       short* __restrict__ Wt1a, short* __restrict__ Wt1b,
                       short* __restrict__ Wtf) {
    int b = blockIdx.x, t = threadIdx.x;
    if (b < NCH) {
        __shared__ int c[256];
        c[t] = 0;
        __syncthreads();
        int base = b * CHUNK;
        int n = NE - base; if (n > CHUNK) n = CHUNK;
        for (int i = t; i < n; i += 256) atomicAdd(&c[dst[base + i] >> 8], 1);
        __syncthreads();
        part[b * 256 + t] = c[t];
    } else if (b < 196 + 3125) {
        int i = (b - 196) * 256 + t;  // over NN*16 = 800000 float4s
        if (i < NN * 16) {
            f32x4 v = *(const f32x4*)(x + (size_t)i * 4);
            s16x4 ov;
            #pragma unroll
            for (int j = 0; j < 4; j++) ov[j] = f2bs(v[j]);
            *(s16x4*)((short*)Xb + (size_t)i * 4) = ov;
        }
    } else {
        int wb = b - 3321;
        if (wb < 4) {
            const float* W = wb == 0 ? w0a : wb == 1 ? w0b : wb == 2 ? w1a : w1b;
            short* Wt = wb == 0 ? Wt0a : wb == 1 ? Wt0b : wb == 2 ? Wt1a : Wt1b;
            for (int e = t; e < 4096; e += 256) {
                int k = e >> 6, n = e & 63;
                Wt[n * 64 + k] = f2bs(W[e]);
            }
        } else {
            for (int e = t; e < 8192; e += 256) {
                int k = e >> 6, n = e & 63;
                Wtf[n * 128 + k] = f2bs(lw[e]);
            }
        }
    }
}

// ---- scan bucket totals (sum part over chunks) -> bbase/bres; zero sums -------
__global__ void bscan_k(const int* __restrict__ part, int* __restrict__ bbase,
                        int* __restrict__ bres, int* __restrict__ off,
                        float* __restrict__ sums) {
    __shared__ int s[256];
    int t = threadIdx.x;
    int v = 0;
    for (int c = 0; c < NCH; c++) v += part[c * 256 + t];
    s[t] = v;
    __syncthreads();
    for (int d = 1; d < 256; d <<= 1) {
        int u = (t >= d) ? s[t - d] : 0;
        __syncthreads();
        s[t] += u;
        __syncthreads();
    }
    int ex = s[t] - v;
    bbase[t] = ex;
    bres[t] = ex;
    if (t == 0) { bbase[256] = NE; off[NN] = NE; }
    sums[t] = 0.f; sums[256 + t] = 0.f;  // 512 floats total
}

// ---- bucket scatter: chunk -> bucket-ordered ebuf (coalesced writes) ----------
// packed int: src (16b) | dst&255 (8b) | bucket (8b)
__global__ void bscatter_k(const int* __restrict__ src, const int* __restrict__ dst,
                           int* __restrict__ bres, int* __restrict__ ebuf) {
    __shared__ int cnt[256], loff[256], lcur[256], gst[256], sc[256];
    __shared__ int packed[CHUNK];
    int t = threadIdx.x;
    cnt[t] = 0;
    __syncthreads();
    int base = blockIdx.x * CHUNK;
    int n = NE - base; if (n > CHUNK) n = CHUNK;
    for (int i = t; i < n; i += 256) atomicAdd(&cnt[dst[base + i] >> 8], 1);
    __syncthreads();
    sc[t] = cnt[t];
    __syncthreads();
    for (int d = 1; d < 256; d <<= 1) {
        int u = (t >= d) ? sc[t - d] : 0;
        __syncthreads();
        sc[t] += u;
        __syncthreads();
    }
    loff[t] = sc[t] - cnt[t];
    lcur[t] = loff[t];
    __syncthreads();
    for (int i = t; i < n; i += 256) {
        int d = dst[base + i];
        int b = d >> 8;
        int p = atomicAdd(&lcur[b], 1);
        packed[p] = src[base + i] | ((d & 255) << 16) | (b << 24);
    }
    __syncthreads();
    if (cnt[t]) gst[t] = atomicAdd(&bres[t], cnt[t]);
    __syncthreads();
    for (int i = t; i < n; i += 256) {
        int v = packed[i];
        int b = (v >> 24) & 255;
        ebuf[gst[b] + i - loff[b]] = v & 0xFFFFFF;
    }
}

// ---- per-bucket CSR: off[] + adj[] --------------------------------------------
__global__ void csr_k(const int* __restrict__ bbase, const int* __restrict__ ebuf,
                      int* __restrict__ off, int* __restrict__ adj) {
    __shared__ int cnt[256], loff[256], lcur[256], sc[256];
    int b = blockIdx.x, t = threadIdx.x;
    int s0 = bbase[b], s1 = bbase[b + 1];
    int n = s1 - s0;
    cnt[t] = 0;
    __syncthreads();
    for (int i = t; i < n; i += 256) atomicAdd(&cnt[(ebuf[s0 + i] >> 16) & 255], 1);
    __syncthreads();
    sc[t] = cnt[t];
    __syncthreads();
    for (int d = 1; d < 256; d <<= 1) {
        int u = (t >= d) ? sc[t - d] : 0;
        __syncthreads();
        sc[t] += u;
        __syncthreads();
    }
    loff[t] = sc[t] - cnt[t];
    lcur[t] = loff[t];
    int node = b * 256 + t;
    if (node < NN) off[node] = s0 + loff[t];
    __syncthreads();
    for (int i = t; i < n; i += 256) {
        int v = ebuf[s0 + i];
        int p = atomicAdd(&lcur[(v >> 16) & 255], 1);
        adj[s0 + p] = v & 0xFFFF;
    }
}

// ---- FUSED gather + MFMA GEMM, K-SPLIT across wave pairs ----------------------
// block = 4 waves = 2 pairs; pair serves 16 nodes (block tile = 32 rows).
// Wave h of a pair gathers features [32h,32h+32) only (1x16B load/edge/lane)
// and runs mfma over its K-half; h=1 ships acc via LDS; h=0 combines+epilogue.
// Doubles gather wave-parallelism (3125 -> 6250 waves) vs the K=64 version.
__global__ void ggemm_k(const __hip_bfloat16* __restrict__ X,
                        const int* __restrict__ off, const int* __restrict__ adj,
                        const short* __restrict__ Wt,    // 64x64 bf16, [n][k]
                        const float* __restrict__ bias,
                        float* __restrict__ T,
                        float* __restrict__ sums) {
    __shared__ float lsum[64], lssq[64];
    __shared__ float accb[2][16][68];   // [pair][row][col], stride 68: 2-way max
    int t = threadIdx.x;
    if (t < 64) { lsum[t] = 0.f; lssq[t] = 0.f; }
    int w = t >> 6;
    int pair = w >> 1, h = w & 1;
    int L = t & 63;
    int m = L & 15, quad = L >> 4;
    int prow = blockIdx.x * 32 + pair * 16;
    int node = prow + m;
    if (node >= NN) node = NN - 1;  // dup row; stores/stats guarded below
    const short* Xp = (const short*)X;
    int kbase = h * 32 + quad * 8;  // this lane's 8-feature slice

    // self row slice
    s16x8 sv = *(const s16x8*)(Xp + (size_t)node * 64 + kbase);
    float a[8];
    #pragma unroll
    for (int j = 0; j < 8; j++) a[j] = bs2f(sv[j]);

    int s = off[node], e = off[node + 1];
    int p = s;
    // 8-edge pipeline: 8 independent 16B loads in flight per lane
    for (; p + 8 <= e; p += 8) {
        int jx[8];
        #pragma unroll
        for (int q = 0; q < 8; q++) jx[q] = adj[p + q];
        s16x8 v[8];
        #pragma unroll
        for (int q = 0; q < 8; q++)
            v[q] = *(const s16x8*)(Xp + (size_t)jx[q] * 64 + kbase);
        #pragma unroll
        for (int j = 0; j < 8; j++) {
            a[j] += ((bs2f(v[0][j]) + bs2f(v[1][j])) + (bs2f(v[2][j]) + bs2f(v[3][j])))
                  + ((bs2f(v[4][j]) + bs2f(v[5][j])) + (bs2f(v[6][j]) + bs2f(v[7][j])));
        }
    }
    for (; p < e; p++) {
        s16x8 v0 = *(const s16x8*)(Xp + (size_t)adj[p] * 64 + kbase);
        #pragma unroll
        for (int j = 0; j < 8; j++) a[j] += bs2f(v0[j]);
    }

    s16x8 a0;
    #pragma unroll
    for (int j = 0; j < 8; j++) a0[j] = f2bs(a[j]);

    // K=32 MFMA on this wave's K-half (B rows kbase..kbase+8 per quad)
    f32x4 acc[4];
    #pragma unroll
    for (int nt = 0; nt < 4; nt++) {
        int n = nt * 16 + m;
        s16x8 b0 = *(const s16x8*)(Wt + n * 64 + kbase);
        acc[nt] = (f32x4){0.f, 0.f, 0.f, 0.f};
        acc[nt] = __builtin_amdgcn_mfma_f32_16x16x32_bf16(a0, b0, acc[nt], 0, 0, 0);
    }

    // h=1 ships partial C to LDS; h=0 combines + epilogue
    if (h == 1) {
        #pragma unroll
        for (int nt = 0; nt < 4; nt++)
            #pragma unroll
            for (int r = 0; r < 4; r++)
                accb[pair][quad * 4 + r][nt * 16 + m] = acc[nt][r];
    }
    __syncthreads();
    if (h == 0) {
        #pragma unroll
        for (int nt = 0; nt < 4; nt++) {
            int col = nt * 16 + m;
            float bv = bias[col];
            float ps = 0.f, pq = 0.f;
            #pragma unroll
            for (int r = 0; r < 4; r++) {
                int orow = prow + quad * 4 + r;
                if (orow < NN) {
                    float vv = acc[nt][r] + accb[pair][quad * 4 + r][col] + bv;
                    T[(size_t)orow * 64 + col] = vv;
                    ps += vv;
                    pq += vv * vv;
                }
            }
            atomicAdd(&lsum[col], ps);
            atomicAdd(&lssq[col], pq);
        }
    }
    __syncthreads();
    if (t < 64) {
        atomicAdd(&sums[t], lsum[t]);
        atomicAdd(&sums[64 + t], lssq[t]);
    }
}

// ---- GEMM with A = relu(bn(T)) built on the fly -> Tout fp32 + stats ----------
__global__ void gemm_bn_k(const float* __restrict__ Tin,
                          const float* __restrict__ stats,
                          const float* __restrict__ g, const float* __restrict__ be,
                          const short* __restrict__ Wt,    // 64x64 bf16 [n][k]
                          const float* __restrict__ bias,
                          float* __restrict__ T,
                          float* __restrict__ sums) {
    __shared__ float sc[64], sh[64], lsum[64], lssq[64];
    int tid = threadIdx.x;
    if (tid < 64) {
        float mm = stats[tid] * (1.0f / NN);
        float var = stats[64 + tid] * (1.0f / NN) - mm * mm;
        if (var < 0.f) var = 0.f;
        float s = g[tid] * rsqrtf(var + BN_EPS);
        sc[tid] = s;
        sh[tid] = be[tid] - mm * s;
        lsum[tid] = 0.f; lssq[tid] = 0.f;
    }
    __syncthreads();
    int wv = tid >> 6, L = tid & 63;
    int m = L & 15, quad = L >> 4;
    int wrow = blockIdx.x * 64 + wv * 16;
    int arow = wrow + m;
    if (arow >= NN) arow = NN - 1;
    f32x4 t0 = *(const f32x4*)(Tin + (size_t)arow * 64 + quad * 8);
    f32x4 t1 = *(const f32x4*)(Tin + (size_t)arow * 64 + quad * 8 + 4);
    f32x4 t2 = *(const f32x4*)(Tin + (size_t)arow * 64 + 32 + quad * 8);
    f32x4 t3 = *(const f32x4*)(Tin + (size_t)arow * 64 + 32 + quad * 8 + 4);
    s16x8 a0, a1;
    #pragma unroll
    for (int j = 0; j < 4; j++) {
        int k0 = quad * 8 + j, k1 = quad * 8 + 4 + j;
        float u0 = t0[j] * sc[k0] + sh[k0]; a0[j]     = f2bs(u0 > 0.f ? u0 : 0.f);
        float u1 = t1[j] * sc[k1] + sh[k1]; a0[4 + j] = f2bs(u1 > 0.f ? u1 : 0.f);
        float u2 = t2[j] * sc[32 + k0] + sh[32 + k0]; a1[j]     = f2bs(u2 > 0.f ? u2 : 0.f);
        float u3 = t3[j] * sc[32 + k1] + sh[32 + k1]; a1[4 + j] = f2bs(u3 > 0.f ? u3 : 0.f);
    }
    f32x4 acc[4];
    #pragma unroll
    for (int nt = 0; nt < 4; nt++) {
        int n = nt * 16 + m;
        s16x8 b0 = *(const s16x8*)(Wt + n * 64 + quad * 8);
        s16x8 b1 = *(const s16x8*)(Wt + n * 64 + 32 + quad * 8);
        acc[nt] = (f32x4){0.f, 0.f, 0.f, 0.f};
        acc[nt] = __builtin_amdgcn_mfma_f32_16x16x32_bf16(a0, b0, acc[nt], 0, 0, 0);
        acc[nt] = __builtin_amdgcn_mfma_f32_16x16x32_bf16(a1, b1, acc[nt], 0, 0, 0);
    }
    #pragma unroll
    for (int nt = 0; nt < 4; nt++) {
        int col = nt * 16 + m;
        float bv = bias[col];
        float ps = 0.f, pq = 0.f;
        #pragma unroll
        for (int r = 0; r < 4; r++) {
            int orow = wrow + quad * 4 + r;
            if (orow < NN) {
                float v = acc[nt][r] + bv;
                T[(size_t)orow * 64 + col] = v;
                ps += v;
                pq += v * v;
            }
        }
        atomicAdd(&lsum[col], ps);
        atomicAdd(&lssq[col], pq);
    }
    __syncthreads();
    if (tid < 64) {
        atomicAdd(&sums[tid], lsum[tid]);
        atomicAdd(&sums[64 + tid], lssq[tid]);
    }
}

// ---- BN finalize + apply + ReLU: T2 fp32 -> HCb bf16 --------------------------
__global__ void bn_k(const float* __restrict__ T, const float* __restrict__ sums,
                     const float* __restrict__ g, const float* __restrict__ be,
                     __hip_bfloat16* __restrict__ Hb) {
    __shared__ float sc[64], sh[64];
    int tid = threadIdx.x;
    if (tid < 64) {
        float m = sums[tid] * (1.0f / NN);
        float var = sums[64 + tid] * (1.0f / NN) - m * m;
        if (var < 0.f) var = 0.f;
        float s = g[tid] * rsqrtf(var + BN_EPS);
        sc[tid] = s;
        sh[tid] = be[tid] - m * s;
    }
    __syncthreads();
    int i = blockIdx.x * 256 + tid;  // over NN*16 float4s
    if (i < NN * 16) {
        int row = i >> 4, f = (i & 15) * 4;
        f32x4 v = *(const f32x4*)(T + (size_t)row * 64 + f);
        s16x4 ub;
        #pragma unroll
        for (int j = 0; j < 4; j++) {
            float w = v[j] * sc[f + j] + sh[f + j];
            ub[j] = f2bs(w > 0.f ? w : 0.f);
        }
        *(s16x4*)((short*)Hb + (size_t)row * 64 + f) = ub;
    }
}

// ---- final MFMA GEMM: [h1(bf16) | relu(bn(T2))] (Nx128) @ Wtf -> fp32 out -----
__global__ void gemm_fin_k(const __hip_bfloat16* __restrict__ H1b,
                           const float* __restrict__ T2,
                           const float* __restrict__ stats,
                           const float* __restrict__ g, const float* __restrict__ be,
                           const short* __restrict__ Wtf,   // [n][k], k=128, bf16
                           const float* __restrict__ bias,
                           float* __restrict__ O) {
    __shared__ float sc[64], sh[64];
    int tid = threadIdx.x;
    if (tid < 64) {
        float mm = stats[tid] * (1.0f / NN);
        float var = stats[64 + tid] * (1.0f / NN) - mm * mm;
        if (var < 0.f) var = 0.f;
        float s = g[tid] * rsqrtf(var + BN_EPS);
        sc[tid] = s;
        sh[tid] = be[tid] - mm * s;
    }
    __syncthreads();
    int wv = tid >> 6, L = tid & 63;
    int m = L & 15, quad = L >> 4;
    int wrow = blockIdx.x * 64 + wv * 16;
    int arow = wrow + m;
    if (arow >= NN) arow = NN - 1;
    const short* Hp = (const short*)H1b;
    s16x8 a0 = *(const s16x8*)(Hp + (size_t)arow * 64 + quad * 8);
    s16x8 a1 = *(const s16x8*)(Hp + (size_t)arow * 64 + 32 + quad * 8);
    f32x4 t0 = *(const f32x4*)(T2 + (size_t)arow * 64 + quad * 8);
    f32x4 t1 = *(const f32x4*)(T2 + (size_t)arow * 64 + quad * 8 + 4);
    f32x4 t2 = *(const f32x4*)(T2 + (size_t)arow * 64 + 32 + quad * 8);
    f32x4 t3 = *(const f32x4*)(T2 + (size_t)arow * 64 + 32 + quad * 8 + 4);
    s16x8 a2, a3;
    #pragma unroll
    for (int j = 0; j < 4; j++) {
        int k0 = quad * 8 + j, k1 = quad * 8 + 4 + j;
        float u0 = t0[j] * sc[k0] + sh[k0]; a2[j]     = f2bs(u0 > 0.f ? u0 : 0.f);
        float u1 = t1[j] * sc[k1] + sh[k1]; a2[4 + j] = f2bs(u1 > 0.f ? u1 : 0.f);
        float u2 = t2[j] * sc[32 + k0] + sh[32 + k0]; a3[j]     = f2bs(u2 > 0.f ? u2 : 0.f);
        float u3 = t3[j] * sc[32 + k1] + sh[32 + k1]; a3[4 + j] = f2bs(u3 > 0.f ? u3 : 0.f);
    }
    f32x4 acc[4];
    #pragma unroll
    for (int nt = 0; nt < 4; nt++) {
        int n = nt * 16 + m;
        s16x8 b0 = *(const s16x8*)(Wtf + n * 128 + quad * 8);
        s16x8 b1 = *(const s16x8*)(Wtf + n * 128 + 32 + quad * 8);
        s16x8 b2 = *(const s16x8*)(Wtf + n * 128 + 64 + quad * 8);
        s16x8 b3 = *(const s16x8*)(Wtf + n * 128 + 96 + quad * 8);
        acc[nt] = (f32x4){0.f, 0.f, 0.f, 0.f};
        acc[nt] = __builtin_amdgcn_mfma_f32_16x16x32_bf16(a0, b0, acc[nt], 0, 0, 0);
        acc[nt] = __builtin_amdgcn_mfma_f32_16x16x32_bf16(a1, b1, acc[nt], 0, 0, 0);
        acc[nt] = __builtin_amdgcn_mfma_f32_16x16x32_bf16(a2, b2, acc[nt], 0, 0, 0);
        acc[nt] = __builtin_amdgcn_mfma_f32_16x16x32_bf16(a3, b3, acc[nt], 0, 0, 0);
    }
    #pragma unroll
    for (int nt = 0; nt < 4; nt++) {
        int col = nt * 16 + m;
        float bv = bias[col];
        #pragma unroll
        for (int r = 0; r < 4; r++) {
            int orow = wrow + quad * 4 + r;
            if (orow < NN) O[(size_t)orow * 64 + col] = acc[nt][r] + bv;
        }
    }
}

// ---------------- launch ----------------
extern "C" void kernel_launch(void* const* d_in, const int* in_sizes, int n_in,
                              void* d_out, int out_size, void* d_ws, size_t ws_size,
                              hipStream_t stream) {
    const float* x   = (const float*)d_in[0];
    const int*   ei  = (const int*)d_in[1];
    const float* w0a = (const float*)d_in[2];
    const float* b0a = (const float*)d_in[3];
    const float* g0a = (const float*)d_in[4];
    const float* be0a= (const float*)d_in[5];
    const float* w0b = (const float*)d_in[6];
    const float* b0b = (const float*)d_in[7];
    const float* g0b = (const float*)d_in[8];
    const float* be0b= (const float*)d_in[9];
    const float* w1a = (const float*)d_in[10];
    const float* b1a = (const float*)d_in[11];
    const float* g1a = (const float*)d_in[12];
    const float* be1a= (const float*)d_in[13];
    const float* w1b = (const float*)d_in[14];
    const float* b1b = (const float*)d_in[15];
    const float* g1b = (const float*)d_in[16];
    const float* be1b= (const float*)d_in[17];
    const float* lw  = (const float*)d_in[18];
    const float* lb  = (const float*)d_in[19];
    float* out = (float*)d_out;
    (void)in_sizes; (void)n_in; (void)out_size; (void)ws_size;

    char* wsb = (char*)d_ws;
    size_t o = 0;
    auto alloc = [&](size_t bytes) -> char* {
        char* p = wsb + o;
        o += (bytes + 255) & ~(size_t)255;
        return p;
    };
    int* part = (int*)alloc(NCH * 256 * 4);
    float* sums = (float*)alloc(512 * 4);
    int* bbase = (int*)alloc(257 * 4);
    int* bres = (int*)alloc(256 * 4);
    int* off = (int*)alloc((NN + 1) * 4);
    int* adj = (int*)alloc(NE * 4);
    int* ebuf = (int*)alloc(NE * 4);
    __hip_bfloat16* Xb  = (__hip_bfloat16*)alloc((size_t)NN * 64 * 2);
    __hip_bfloat16* HCb = (__hip_bfloat16*)alloc((size_t)NN * 64 * 2);
    float* T  = (float*)alloc((size_t)NN * 64 * 4);
    float* T2 = (float*)alloc((size_t)NN * 64 * 4);
    short* Wt0a = (short*)alloc(4096 * 2);
    short* Wt0b = (short*)alloc(4096 * 2);
    short* Wt1a = (short*)alloc(4096 * 2);
    short* Wt1b = (short*)alloc(4096 * 2);
    short* Wtf  = (short*)alloc(8192 * 2);

    const int* src = ei;
    const int* dst = ei + NE;

    prep_k<<<3326, 256, 0, stream>>>(dst, part, x, Xb, w0a, w0b, w1a, w1b, lw,
                                     Wt0a, Wt0b, Wt1a, Wt1b, Wtf);
    bscan_k<<<1, 256, 0, stream>>>(part, bbase, bres, off, sums);
    bscatter_k<<<NCH, 256, 0, stream>>>(src, dst, bres, ebuf);
    csr_k<<<NBK, 256, 0, stream>>>(bbase, ebuf, off, adj);

    const int ggrid = (NN + 31) / 32;          // 1563 (32 rows per block)
    const int mgrid = (NN + 63) / 64;          // 782
    const int agrid = (NN * 16 + 255) / 256;   // 3125

    // ---- layer 0 ----
    ggemm_k<<<ggrid, 256, 0, stream>>>(Xb, off, adj, Wt0a, b0a, T, sums + 0);
    gemm_bn_k<<<mgrid, 256, 0, stream>>>(T, sums + 0, g0a, be0a, Wt0b, b0b, T2, sums + 128);
    bn_k<<<agrid, 256, 0, stream>>>(T2, sums + 128, g0b, be0b, HCb);          // h1 bf16

    // ---- layer 1 ----
    ggemm_k<<<ggrid, 256, 0, stream>>>(HCb, off, adj, Wt1a, b1a, T, sums + 256);
    gemm_bn_k<<<mgrid, 256, 0, stream>>>(T, sums + 256, g1a, be1a, Wt1b, b1b, T2, sums + 384);

    // ---- JK cat + final linear (h2 BN fused; h1 read as bf16) ----
    gemm_fin_k<<<mgrid, 256, 0, stream>>>(HCb, T2, sums + 384, g1b, be1b, Wtf, lb, out);
}

// Round 16
// 343.238 us; speedup vs baseline: 1.0536x; 1.0536x over previous
//
#include <hip/hip_runtime.h>
#include <hip/hip_bf16.h>

#define NN 50000
#define NE 800000
#define BN_EPS 1e-5f
#define CHUNK 4096
#define NCH 196    // ceil(NE / CHUNK) = 196 (196*4096 = 802816)
#define NBK 196    // ceil(NN / 256) dst-buckets

typedef __attribute__((ext_vector_type(4))) float f32x4;
typedef __attribute__((ext_vector_type(8))) short s16x8;   // 8 bf16 = MFMA A/B frag
typedef __attribute__((ext_vector_type(4))) short s16x4;

__device__ __forceinline__ float bf2f(__hip_bfloat16 v) { return __bfloat162float(v); }
__device__ __forceinline__ float bs2f(short v) {
    unsigned u = ((unsigned)(unsigned short)v) << 16;
    return __builtin_bit_cast(float, u);
}
__device__ __forceinline__ short f2bs(float v) {
    __hip_bfloat16 b = __float2bfloat16(v);
    return __builtin_bit_cast(short, b);
}

// ---- prep: [0,196) bhist chunks -> part; [196,3321) cvt x->Xb; [3321,3326) W^T->bf16
__global__ void prep_k(const int* __restrict__ dst, int* __restrict__ part,
                       const float* __restrict__ x, __hip_bfloat16* __restrict__ Xb,
                       const float* __restrict__ w0a, const float* __restrict__ w0b,
                       const float* __restrict__ w1a, const float* __restrict__ w1b,
                       const float* __restrict__ lw,
                       short* __restrict__ Wt0a, short* __restrict__ Wt0b,
                       short* __restrict__ Wt1a, short* __restrict__ Wt1b,
                       short* __restrict__ Wtf) {
    int b = blockIdx.x, t = threadIdx.x;
    if (b < NCH) {
        __shared__ int c[256];
        c[t] = 0;
        __syncthreads();
        int base = b * CHUNK;
        int n = NE - base; if (n > CHUNK) n = CHUNK;
        for (int i = t; i < n; i += 256) atomicAdd(&c[dst[base + i] >> 8], 1);
        __syncthreads();
        part[b * 256 + t] = c[t];
    } else if (b < 196 + 3125) {
        int i = (b - 196) * 256 + t;  // over NN*16 = 800000 float4s
        if (i < NN * 16) {
            f32x4 v = *(const f32x4*)(x + (size_t)i * 4);
            s16x4 ov;
            #pragma unroll
            for (int j = 0; j < 4; j++) ov[j] = f2bs(v[j]);
            *(s16x4*)((short*)Xb + (size_t)i * 4) = ov;
        }
    } else {
        int wb = b - 3321;
        if (wb < 4) {
            const float* W = wb == 0 ? w0a : wb == 1 ? w0b : wb == 2 ? w1a : w1b;
            short* Wt = wb == 0 ? Wt0a : wb == 1 ? Wt0b : wb == 2 ? Wt1a : Wt1b;
            for (int e = t; e < 4096; e += 256) {
                int k = e >> 6, n = e & 63;
                Wt[n * 64 + k] = f2bs(W[e]);
            }
        } else {
            for (int e = t; e < 8192; e += 256) {
                int k = e >> 6, n = e & 63;
                Wtf[n * 128 + k] = f2bs(lw[e]);
            }
        }
    }
}

// ---- scan bucket totals (sum part over chunks) -> bbase/bres; zero sums -------
__global__ void bscan_k(const int* __restrict__ part, int* __restrict__ bbase,
                        int* __restrict__ bres, int* __restrict__ off,
                        float* __restrict__ sums) {
    __shared__ int s[256];
    int t = threadIdx.x;
    int v = 0;
    for (int c = 0; c < NCH; c++) v += part[c * 256 + t];
    s[t] = v;
    __syncthreads();
    for (int d = 1; d < 256; d <<= 1) {
        int u = (t >= d) ? s[t - d] : 0;
        __syncthreads();
        s[t] += u;
        __syncthreads();
    }
    int ex = s[t] - v;
    bbase[t] = ex;
    bres[t] = ex;
    if (t == 0) { bbase[256] = NE; off[NN] = NE; }
    sums[t] = 0.f; sums[256 + t] = 0.f;  // 512 floats total
}

// ---- bucket scatter: chunk -> bucket-ordered ebuf (coalesced writes) ----------
// packed int: src (16b) | dst&255 (8b) | bucket (8b)
__global__ void bscatter_k(const int* __restrict__ src, const int* __restrict__ dst,
                           int* __restrict__ bres, int* __restrict__ ebuf) {
    __shared__ int cnt[256], loff[256], lcur[256], gst[256], sc[256];
    __shared__ int packed[CHUNK];
    int t = threadIdx.x;
    cnt[t] = 0;
    __syncthreads();
    int base = blockIdx.x * CHUNK;
    int n = NE - base; if (n > CHUNK) n = CHUNK;
    for (int i = t; i < n; i += 256) atomicAdd(&cnt[dst[base + i] >> 8], 1);
    __syncthreads();
    sc[t] = cnt[t];
    __syncthreads();
    for (int d = 1; d < 256; d <<= 1) {
        int u = (t >= d) ? sc[t - d] : 0;
        __syncthreads();
        sc[t] += u;
        __syncthreads();
    }
    loff[t] = sc[t] - cnt[t];
    lcur[t] = loff[t];
    __syncthreads();
    for (int i = t; i < n; i += 256) {
        int d = dst[base + i];
        int b = d >> 8;
        int p = atomicAdd(&lcur[b], 1);
        packed[p] = src[base + i] | ((d & 255) << 16) | (b << 24);
    }
    __syncthreads();
    if (cnt[t]) gst[t] = atomicAdd(&bres[t], cnt[t]);
    __syncthreads();
    for (int i = t; i < n; i += 256) {
        int v = packed[i];
        int b = (v >> 24) & 255;
        ebuf[gst[b] + i - loff[b]] = v & 0xFFFFFF;
    }
}

// ---- per-bucket CSR: off[] + adj[] --------------------------------------------
__global__ void csr_k(const int* __restrict__ bbase, const int* __restrict__ ebuf,
                      int* __restrict__ off, int* __restrict__ adj) {
    __shared__ int cnt[256], loff[256], lcur[256], sc[256];
    int b = blockIdx.x, t = threadIdx.x;
    int s0 = bbase[b], s1 = bbase[b + 1];
    int n = s1 - s0;
    cnt[t] = 0;
    __syncthreads();
    for (int i = t; i < n; i += 256) atomicAdd(&cnt[(ebuf[s0 + i] >> 16) & 255], 1);
    __syncthreads();
    sc[t] = cnt[t];
    __syncthreads();
    for (int d = 1; d < 256; d <<= 1) {
        int u = (t >= d) ? sc[t - d] : 0;
        __syncthreads();
        sc[t] += u;
        __syncthreads();
    }
    loff[t] = sc[t] - cnt[t];
    lcur[t] = loff[t];
    int node = b * 256 + t;
    if (node < NN) off[node] = s0 + loff[t];
    __syncthreads();
    for (int i = t; i < n; i += 256) {
        int v = ebuf[s0 + i];
        int p = atomicAdd(&lcur[(v >> 16) & 255], 1);
        adj[s0 + p] = v & 0xFFFF;
    }
}

// ---- FUSED gather + MFMA GEMM, EDGE-SPLIT across wave pairs -------------------
// block = 4 waves = 2 pairs; pair serves 16 nodes (block tile = 32 rows).
// Wave h of a pair processes edge range [s,mid)/[mid,e) with FULL K (2x16B
// loads/edge/lane, full 128B row per request): per-wave dependent chain
// HALVES vs round 14 while keeping its line utilization. Wave 1 ships fp32
// partials via LDS; wave 0 adds self+partner, does K=64 MFMA + epilogue.
__global__ void ggemm_k(const __hip_bfloat16* __restrict__ X,
                        const int* __restrict__ off, const int* __restrict__ adj,
                        const short* __restrict__ Wt,    // 64x64 bf16, [n][k]
                        const float* __restrict__ bias,
                        float* __restrict__ T,
                        float* __restrict__ sums) {
    __shared__ float lsum[64], lssq[64];
    __shared__ float pacc[2][16 * 68];  // [pair][node*68 + feat], <=2-way banks
    int t = threadIdx.x;
    if (t < 64) { lsum[t] = 0.f; lssq[t] = 0.f; }
    int w = t >> 6, pair = w >> 1, h = w & 1;
    int L = t & 63, m = L & 15, quad = L >> 4;
    int prow = blockIdx.x * 32 + pair * 16;
    int node = prow + m;
    if (node >= NN) node = NN - 1;  // dup row; stores/stats guarded below
    const short* Xp = (const short*)X;

    float aL[8], aH[8];
    int s0 = off[node], e0 = off[node + 1];
    int mid = s0 + ((e0 - s0) >> 1);
    int ps, pe;
    if (h == 0) {
        const short* rp = Xp + (size_t)node * 64 + quad * 8;
        s16x8 sv = *(const s16x8*)rp;
        s16x8 sw = *(const s16x8*)(rp + 32);
        #pragma unroll
        for (int j = 0; j < 8; j++) { aL[j] = bs2f(sv[j]); aH[j] = bs2f(sw[j]); }
        ps = s0; pe = mid;
    } else {
        #pragma unroll
        for (int j = 0; j < 8; j++) { aL[j] = 0.f; aH[j] = 0.f; }
        ps = mid; pe = e0;
    }

    int p = ps;
    for (; p + 8 <= pe; p += 8) {
        int jx[8];
        #pragma unroll
        for (int q = 0; q < 8; q++) jx[q] = adj[p + q];
        s16x8 v[8], wv[8];
        #pragma unroll
        for (int q = 0; q < 8; q++) {
            const short* r = Xp + (size_t)jx[q] * 64 + quad * 8;
            v[q] = *(const s16x8*)r;
            wv[q] = *(const s16x8*)(r + 32);
        }
        #pragma unroll
        for (int j = 0; j < 8; j++) {
            aL[j] += ((bs2f(v[0][j]) + bs2f(v[1][j])) + (bs2f(v[2][j]) + bs2f(v[3][j])))
                   + ((bs2f(v[4][j]) + bs2f(v[5][j])) + (bs2f(v[6][j]) + bs2f(v[7][j])));
            aH[j] += ((bs2f(wv[0][j]) + bs2f(wv[1][j])) + (bs2f(wv[2][j]) + bs2f(wv[3][j])))
                   + ((bs2f(wv[4][j]) + bs2f(wv[5][j])) + (bs2f(wv[6][j]) + bs2f(wv[7][j])));
        }
    }
    if (p + 4 <= pe) {
        int j0 = adj[p], j1 = adj[p + 1], j2 = adj[p + 2], j3 = adj[p + 3];
        const short* r0 = Xp + (size_t)j0 * 64 + quad * 8;
        const short* r1 = Xp + (size_t)j1 * 64 + quad * 8;
        const short* r2 = Xp + (size_t)j2 * 64 + quad * 8;
        const short* r3 = Xp + (size_t)j3 * 64 + quad * 8;
        s16x8 v0 = *(const s16x8*)r0, w0 = *(const s16x8*)(r0 + 32);
        s16x8 v1 = *(const s16x8*)r1, w1 = *(const s16x8*)(r1 + 32);
        s16x8 v2 = *(const s16x8*)r2, w2 = *(const s16x8*)(r2 + 32);
        s16x8 v3 = *(const s16x8*)r3, w3 = *(const s16x8*)(r3 + 32);
        #pragma unroll
        for (int j = 0; j < 8; j++) {
            aL[j] += (bs2f(v0[j]) + bs2f(v1[j])) + (bs2f(v2[j]) + bs2f(v3[j]));
            aH[j] += (bs2f(w0[j]) + bs2f(w1[j])) + (bs2f(w2[j]) + bs2f(w3[j]));
        }
        p += 4;
    }
    for (; p < pe; p++) {
        const short* r0 = Xp + (size_t)adj[p] * 64 + quad * 8;
        s16x8 v0 = *(const s16x8*)r0, w0 = *(const s16x8*)(r0 + 32);
        #pragma unroll
        for (int j = 0; j < 8; j++) { aL[j] += bs2f(v0[j]); aH[j] += bs2f(w0[j]); }
    }

    // combine: wave1 -> LDS, wave0 adds and finishes
    if (h == 1) {
        float* dstp = &pacc[pair][m * 68];
        #pragma unroll
        for (int j = 0; j < 8; j++) {
            dstp[quad * 8 + j] = aL[j];
            dstp[32 + quad * 8 + j] = aH[j];
        }
    }
    __syncthreads();
    if (h == 0) {
        const float* srcp = &pacc[pair][m * 68];
        #pragma unroll
        for (int j = 0; j < 8; j++) {
            aL[j] += srcp[quad * 8 + j];
            aH[j] += srcp[32 + quad * 8 + j];
        }
        s16x8 a0, a1;
        #pragma unroll
        for (int j = 0; j < 8; j++) { a0[j] = f2bs(aL[j]); a1[j] = f2bs(aH[j]); }

        f32x4 acc[4];
        #pragma unroll
        for (int nt = 0; nt < 4; nt++) {
            int n = nt * 16 + m;
            s16x8 b0 = *(const s16x8*)(Wt + n * 64 + quad * 8);
            s16x8 b1 = *(const s16x8*)(Wt + n * 64 + 32 + quad * 8);
            acc[nt] = (f32x4){0.f, 0.f, 0.f, 0.f};
            acc[nt] = __builtin_amdgcn_mfma_f32_16x16x32_bf16(a0, b0, acc[nt], 0, 0, 0);
            acc[nt] = __builtin_amdgcn_mfma_f32_16x16x32_bf16(a1, b1, acc[nt], 0, 0, 0);
        }
        #pragma unroll
        for (int nt = 0; nt < 4; nt++) {
            int col = nt * 16 + m;
            float bv = bias[col];
            float pss = 0.f, pq = 0.f;
            #pragma unroll
            for (int r = 0; r < 4; r++) {
                int orow = prow + quad * 4 + r;
                if (orow < NN) {
                    float vv = acc[nt][r] + bv;
                    T[(size_t)orow * 64 + col] = vv;
                    pss += vv;
                    pq += vv * vv;
                }
            }
            atomicAdd(&lsum[col], pss);
            atomicAdd(&lssq[col], pq);
        }
    }
    __syncthreads();
    if (t < 64) {
        atomicAdd(&sums[t], lsum[t]);
        atomicAdd(&sums[64 + t], lssq[t]);
    }
}

// ---- GEMM with A = relu(bn(T)) built on the fly -> Tout fp32 + stats ----------
__global__ void gemm_bn_k(const float* __restrict__ Tin,
                          const float* __restrict__ stats,
                          const float* __restrict__ g, const float* __restrict__ be,
                          const short* __restrict__ Wt,    // 64x64 bf16 [n][k]
                          const float* __restrict__ bias,
                          float* __restrict__ T,
                          float* __restrict__ sums) {
    __shared__ float sc[64], sh[64], lsum[64], lssq[64];
    int tid = threadIdx.x;
    if (tid < 64) {
        float mm = stats[tid] * (1.0f / NN);
        float var = stats[64 + tid] * (1.0f / NN) - mm * mm;
        if (var < 0.f) var = 0.f;
        float s = g[tid] * rsqrtf(var + BN_EPS);
        sc[tid] = s;
        sh[tid] = be[tid] - mm * s;
        lsum[tid] = 0.f; lssq[tid] = 0.f;
    }
    __syncthreads();
    int wv = tid >> 6, L = tid & 63;
    int m = L & 15, quad = L >> 4;
    int wrow = blockIdx.x * 64 + wv * 16;
    int arow = wrow + m;
    if (arow >= NN) arow = NN - 1;
    f32x4 t0 = *(const f32x4*)(Tin + (size_t)arow * 64 + quad * 8);
    f32x4 t1 = *(const f32x4*)(Tin + (size_t)arow * 64 + quad * 8 + 4);
    f32x4 t2 = *(const f32x4*)(Tin + (size_t)arow * 64 + 32 + quad * 8);
    f32x4 t3 = *(const f32x4*)(Tin + (size_t)arow * 64 + 32 + quad * 8 + 4);
    s16x8 a0, a1;
    #pragma unroll
    for (int j = 0; j < 4; j++) {
        int k0 = quad * 8 + j, k1 = quad * 8 + 4 + j;
        float u0 = t0[j] * sc[k0] + sh[k0]; a0[j]     = f2bs(u0 > 0.f ? u0 : 0.f);
        float u1 = t1[j] * sc[k1] + sh[k1]; a0[4 + j] = f2bs(u1 > 0.f ? u1 : 0.f);
        float u2 = t2[j] * sc[32 + k0] + sh[32 + k0]; a1[j]     = f2bs(u2 > 0.f ? u2 : 0.f);
        float u3 = t3[j] * sc[32 + k1] + sh[32 + k1]; a1[4 + j] = f2bs(u3 > 0.f ? u3 : 0.f);
    }
    f32x4 acc[4];
    #pragma unroll
    for (int nt = 0; nt < 4; nt++) {
        int n = nt * 16 + m;
        s16x8 b0 = *(const s16x8*)(Wt + n * 64 + quad * 8);
        s16x8 b1 = *(const s16x8*)(Wt + n * 64 + 32 + quad * 8);
        acc[nt] = (f32x4){0.f, 0.f, 0.f, 0.f};
        acc[nt] = __builtin_amdgcn_mfma_f32_16x16x32_bf16(a0, b0, acc[nt], 0, 0, 0);
        acc[nt] = __builtin_amdgcn_mfma_f32_16x16x32_bf16(a1, b1, acc[nt], 0, 0, 0);
    }
    #pragma unroll
    for (int nt = 0; nt < 4; nt++) {
        int col = nt * 16 + m;
        float bv = bias[col];
        float ps = 0.f, pq = 0.f;
        #pragma unroll
        for (int r = 0; r < 4; r++) {
            int orow = wrow + quad * 4 + r;
            if (orow < NN) {
                float v = acc[nt][r] + bv;
                T[(size_t)orow * 64 + col] = v;
                ps += v;
                pq += v * v;
            }
        }
        atomicAdd(&lsum[col], ps);
        atomicAdd(&lssq[col], pq);
    }
    __syncthreads();
    if (tid < 64) {
        atomicAdd(&sums[tid], lsum[tid]);
        atomicAdd(&sums[64 + tid], lssq[tid]);
    }
}

// ---- BN finalize + apply + ReLU: T2 fp32 -> HCb bf16 --------------------------
__global__ void bn_k(const float* __restrict__ T, const float* __restrict__ sums,
                     const float* __restrict__ g, const float* __restrict__ be,
                     __hip_bfloat16* __restrict__ Hb) {
    __shared__ float sc[64], sh[64];
    int tid = threadIdx.x;
    if (tid < 64) {
        float m = sums[tid] * (1.0f / NN);
        float var = sums[64 + tid] * (1.0f / NN) - m * m;
        if (var < 0.f) var = 0.f;
        float s = g[tid] * rsqrtf(var + BN_EPS);
        sc[tid] = s;
        sh[tid] = be[tid] - m * s;
    }
    __syncthreads();
    int i = blockIdx.x * 256 + tid;  // over NN*16 float4s
    if (i < NN * 16) {
        int row = i >> 4, f = (i & 15) * 4;
        f32x4 v = *(const f32x4*)(T + (size_t)row * 64 + f);
        s16x4 ub;
        #pragma unroll
        for (int j = 0; j < 4; j++) {
            float w = v[j] * sc[f + j] + sh[f + j];
            ub[j] = f2bs(w > 0.f ? w : 0.f);
        }
        *(s16x4*)((short*)Hb + (size_t)row * 64 + f) = ub;
    }
}

// ---- final MFMA GEMM: [h1(bf16) | relu(bn(T2))] (Nx128) @ Wtf -> fp32 out -----
__global__ void gemm_fin_k(const __hip_bfloat16* __restrict__ H1b,
                           const float* __restrict__ T2,
                           const float* __restrict__ stats,
                           const float* __restrict__ g, const float* __restrict__ be,
                           const short* __restrict__ Wtf,   // [n][k], k=128, bf16
                           const float* __restrict__ bias,
                           float* __restrict__ O) {
    __shared__ float sc[64], sh[64];
    int tid = threadIdx.x;
    if (tid < 64) {
        float mm = stats[tid] * (1.0f / NN);
        float var = stats[64 + tid] * (1.0f / NN) - mm * mm;
        if (var < 0.f) var = 0.f;
        float s = g[tid] * rsqrtf(var + BN_EPS);
        sc[tid] = s;
        sh[tid] = be[tid] - mm * s;
    }
    __syncthreads();
    int wv = tid >> 6, L = tid & 63;
    int m = L & 15, quad = L >> 4;
    int wrow = blockIdx.x * 64 + wv * 16;
    int arow = wrow + m;
    if (arow >= NN) arow = NN - 1;
    const short* Hp = (const short*)H1b;
    s16x8 a0 = *(const s16x8*)(Hp + (size_t)arow * 64 + quad * 8);
    s16x8 a1 = *(const s16x8*)(Hp + (size_t)arow * 64 + 32 + quad * 8);
    f32x4 t0 = *(const f32x4*)(T2 + (size_t)arow * 64 + quad * 8);
    f32x4 t1 = *(const f32x4*)(T2 + (size_t)arow * 64 + quad * 8 + 4);
    f32x4 t2 = *(const f32x4*)(T2 + (size_t)arow * 64 + 32 + quad * 8);
    f32x4 t3 = *(const f32x4*)(T2 + (size_t)arow * 64 + 32 + quad * 8 + 4);
    s16x8 a2, a3;
    #pragma unroll
    for (int j = 0; j < 4; j++) {
        int k0 = quad * 8 + j, k1 = quad * 8 + 4 + j;
        float u0 = t0[j] * sc[k0] + sh[k0]; a2[j]     = f2bs(u0 > 0.f ? u0 : 0.f);
        float u1 = t1[j] * sc[k1] + sh[k1]; a2[4 + j] = f2bs(u1 > 0.f ? u1 : 0.f);
        float u2 = t2[j] * sc[32 + k0] + sh[32 + k0]; a3[j]     = f2bs(u2 > 0.f ? u2 : 0.f);
        float u3 = t3[j] * sc[32 + k1] + sh[32 + k1]; a3[4 + j] = f2bs(u3 > 0.f ? u3 : 0.f);
    }
    f32x4 acc[4];
    #pragma unroll
    for (int nt = 0; nt < 4; nt++) {
        int n = nt * 16 + m;
        s16x8 b0 = *(const s16x8*)(Wtf + n * 128 + quad * 8);
        s16x8 b1 = *(const s16x8*)(Wtf + n * 128 + 32 + quad * 8);
        s16x8 b2 = *(const s16x8*)(Wtf + n * 128 + 64 + quad * 8);
        s16x8 b3 = *(const s16x8*)(Wtf + n * 128 + 96 + quad * 8);
        acc[nt] = (f32x4){0.f, 0.f, 0.f, 0.f};
        acc[nt] = __builtin_amdgcn_mfma_f32_16x16x32_bf16(a0, b0, acc[nt], 0, 0, 0);
        acc[nt] = __builtin_amdgcn_mfma_f32_16x16x32_bf16(a1, b1, acc[nt], 0, 0, 0);
        acc[nt] = __builtin_amdgcn_mfma_f32_16x16x32_bf16(a2, b2, acc[nt], 0, 0, 0);
        acc[nt] = __builtin_amdgcn_mfma_f32_16x16x32_bf16(a3, b3, acc[nt], 0, 0, 0);
    }
    #pragma unroll
    for (int nt = 0; nt < 4; nt++) {
        int col = nt * 16 + m;
        float bv = bias[col];
        #pragma unroll
        for (int r = 0; r < 4; r++) {
            int orow = wrow + quad * 4 + r;
            if (orow < NN) O[(size_t)orow * 64 + col] = acc[nt][r] + bv;
        }
    }
}

// ---------------- launch ----------------
extern "C" void kernel_launch(void* const* d_in, const int* in_sizes, int n_in,
                              void* d_out, int out_size, void* d_ws, size_t ws_size,
                              hipStream_t stream) {
    const float* x   = (const float*)d_in[0];
    const int*   ei  = (const int*)d_in[1];
    const float* w0a = (const float*)d_in[2];
    const float* b0a = (const float*)d_in[3];
    const float* g0a = (const float*)d_in[4];
    const float* be0a= (const float*)d_in[5];
    const float* w0b = (const float*)d_in[6];
    const float* b0b = (const float*)d_in[7];
    const float* g0b = (const float*)d_in[8];
    const float* be0b= (const float*)d_in[9];
    const float* w1a = (const float*)d_in[10];
    const float* b1a = (const float*)d_in[11];
    const float* g1a = (const float*)d_in[12];
    const float* be1a= (const float*)d_in[13];
    const float* w1b = (const float*)d_in[14];
    const float* b1b = (const float*)d_in[15];
    const float* g1b = (const float*)d_in[16];
    const float* be1b= (const float*)d_in[17];
    const float* lw  = (const float*)d_in[18];
    const float* lb  = (const float*)d_in[19];
    float* out = (float*)d_out;
    (void)in_sizes; (void)n_in; (void)out_size; (void)ws_size;

    char* wsb = (char*)d_ws;
    size_t o = 0;
    auto alloc = [&](size_t bytes) -> char* {
        char* p = wsb + o;
        o += (bytes + 255) & ~(size_t)255;
        return p;
    };
    int* part = (int*)alloc(NCH * 256 * 4);
    float* sums = (float*)alloc(512 * 4);
    int* bbase = (int*)alloc(257 * 4);
    int* bres = (int*)alloc(256 * 4);
    int* off = (int*)alloc((NN + 1) * 4);
    int* adj = (int*)alloc(NE * 4);
    int* ebuf = (int*)alloc(NE * 4);
    __hip_bfloat16* Xb  = (__hip_bfloat16*)alloc((size_t)NN * 64 * 2);
    __hip_bfloat16* HCb = (__hip_bfloat16*)alloc((size_t)NN * 64 * 2);
    float* T  = (float*)alloc((size_t)NN * 64 * 4);
    float* T2 = (float*)alloc((size_t)NN * 64 * 4);
    short* Wt0a = (short*)alloc(4096 * 2);
    short* Wt0b = (short*)alloc(4096 * 2);
    short* Wt1a = (short*)alloc(4096 * 2);
    short* Wt1b = (short*)alloc(4096 * 2);
    short* Wtf  = (short*)alloc(8192 * 2);

    const int* src = ei;
    const int* dst = ei + NE;

    prep_k<<<3326, 256, 0, stream>>>(dst, part, x, Xb, w0a, w0b, w1a, w1b, lw,
                                     Wt0a, Wt0b, Wt1a, Wt1b, Wtf);
    bscan_k<<<1, 256, 0, stream>>>(part, bbase, bres, off, sums);
    bscatter_k<<<NCH, 256, 0, stream>>>(src, dst, bres, ebuf);
    csr_k<<<NBK, 256, 0, stream>>>(bbase, ebuf, off, adj);

    const int ggrid = (NN + 31) / 32;          // 1563 (32 rows per block)
    const int mgrid = (NN + 63) / 64;          // 782
    const int agrid = (NN * 16 + 255) / 256;   // 3125

    // ---- layer 0 ----
    ggemm_k<<<ggrid, 256, 0, stream>>>(Xb, off, adj, Wt0a, b0a, T, sums + 0);
    gemm_bn_k<<<mgrid, 256, 0, stream>>>(T, sums + 0, g0a, be0a, Wt0b, b0b, T2, sums + 128);
    bn_k<<<agrid, 256, 0, stream>>>(T2, sums + 128, g0b, be0b, HCb);          // h1 bf16

    // ---- layer 1 ----
    ggemm_k<<<ggrid, 256, 0, stream>>>(HCb, off, adj, Wt1a, b1a, T, sums + 256);
    gemm_bn_k<<<mgrid, 256, 0, stream>>>(T, sums + 256, g1a, be1a, Wt1b, b1b, T2, sums + 384);

    // ---- JK cat + final linear (h2 BN fused; h1 read as bf16) ----
    gemm_fin_k<<<mgrid, 256, 0, stream>>>(HCb, T2, sums + 384, g1b, be1b, Wtf, lb, out);
}